// Round 5
// baseline (10035.612 us; speedup 1.0000x reference)
//
#include <hip/hip_runtime.h>
#include <cfloat>
#include <climits>

#define NPTS   8192
#define SCENT  2048
#define KNEIGH 32
#define BATCH  4
#define DFEAT  64
#define FPS_T  256
#define NGRP   128     // groups of 64 sorted points
#define GSZ    64
#define NCELL  512     // 8x8x8 Morton cells
#define CAP    64      // fallback candidate capacity

// ---------------------------------------------------------------------------
// Kernel 1: FPS with spatial-group pruning. f32 fast path + exact f64 fallback
// (same proof as R3/R4: candidates dist32 >= v1*(1-2e-6) provably contain the
// f64 argmax; unique winner when v2 < v1*(1-2e-6)). New: points Morton-sorted
// into LDS; per-group (center, radius, max/2nd/argmax of stored dists). Group
// g is provably unchanged by centroid c when (||m_g-c||-r_g)^2*(1-1e-4) >=
// ub1[g]  (margin 1e-4 >> total f32 rounding ~1e-6) -> skip rescan. Only
// dirty groups rescanned (1 wave per group). 2 barriers/iter fast path.
// ---------------------------------------------------------------------------
__global__ __launch_bounds__(FPS_T, 1) void fps_kernel(const float* __restrict__ xyz,
                                                       float* __restrict__ new_xyz) {
    const int b = blockIdx.x, t = threadIdx.x;
    const int lane = t & 63, w = t >> 6;
    const float* X = xyz + (size_t)b * NPTS * 3;

    __shared__ float spx[NPTS], spy[NPTS], spz[NPTS];
    __shared__ float sdist[NPTS];
    __shared__ unsigned short sid[NPTS];      // sorted pos -> original index
    __shared__ unsigned short shist[SCENT];   // selected sorted positions
    __shared__ float gmx[NGRP], gmy[NGRP], gmz[NGRP], gr[NGRP], gub1[NGRP], gub2[NGRP];
    __shared__ int   gai[NGRP];
    __shared__ int   sscratch[1024];          // init: cellcnt[0..511] prefix[512..1023]
    __shared__ unsigned long long smaskv[2];
    __shared__ int   ssel;

    // ---- init: counting sort by 9-bit Morton cell ----
    for (int i = t; i < NCELL; i += FPS_T) { sscratch[i] = 0; sscratch[512 + i] = 0; }
    __syncthreads();
    for (int p = t; p < NPTS; p += FPS_T) {
        float x = X[3 * p], y = X[3 * p + 1], z = X[3 * p + 2];
        int cx = min(max((int)(x + 4.0f), 0), 7);
        int cy = min(max((int)(y + 4.0f), 0), 7);
        int cz = min(max((int)(z + 4.0f), 0), 7);
        int cell = (cx & 1) | ((cy & 1) << 1) | ((cz & 1) << 2)
                 | (((cx >> 1) & 1) << 3) | (((cy >> 1) & 1) << 4) | (((cz >> 1) & 1) << 5)
                 | (((cx >> 2) & 1) << 6) | (((cy >> 2) & 1) << 7) | (((cz >> 2) & 1) << 8);
        atomicAdd(&sscratch[cell], 1);
    }
    __syncthreads();
    if (w == 0) {                              // wave 0: exclusive prefix over 512 cells
        int c[8]; int base = 0;
#pragma unroll
        for (int k = 0; k < 8; ++k) { c[k] = sscratch[lane * 8 + k]; base += c[k]; }
        int run = base;
#pragma unroll
        for (int off = 1; off < 64; off <<= 1) {
            int o = __shfl_up(run, off);
            if (lane >= off) run += o;
        }
        int excl = run - base;
#pragma unroll
        for (int k = 0; k < 8; ++k) { sscratch[512 + lane * 8 + k] = excl; excl += c[k]; }
    }
    __syncthreads();
    for (int i = t; i < NCELL; i += FPS_T) sscratch[i] = 0;
    __syncthreads();
    for (int p = t; p < NPTS; p += FPS_T) {    // scatter
        float x = X[3 * p], y = X[3 * p + 1], z = X[3 * p + 2];
        int cx = min(max((int)(x + 4.0f), 0), 7);
        int cy = min(max((int)(y + 4.0f), 0), 7);
        int cz = min(max((int)(z + 4.0f), 0), 7);
        int cell = (cx & 1) | ((cy & 1) << 1) | ((cz & 1) << 2)
                 | (((cx >> 1) & 1) << 3) | (((cy >> 1) & 1) << 4) | (((cz >> 1) & 1) << 5)
                 | (((cx >> 2) & 1) << 6) | (((cy >> 2) & 1) << 7) | (((cz >> 2) & 1) << 8);
        int pos = sscratch[512 + cell] + atomicAdd(&sscratch[cell], 1);
        spx[pos] = x; spy[pos] = y; spz[pos] = z;
        sid[pos] = (unsigned short)p;
        sdist[pos] = 1e10f;
    }
    __syncthreads();
    for (int p = t; p < NPTS; p += FPS_T)
        if (sid[p] == 0) ssel = p;             // sorted position of original index 0
    if (t < NGRP) {                            // group stats (offset reads: no bank conflict)
        int g = t;
        float ax = 0.f, ay = 0.f, az = 0.f;
#pragma unroll 1
        for (int i = 0; i < GSZ; ++i) {
            int p = g * GSZ + ((i + g) & (GSZ - 1));
            ax += spx[p]; ay += spy[p]; az += spz[p];
        }
        float mx = ax * (1.0f / GSZ), my = ay * (1.0f / GSZ), mz = az * (1.0f / GSZ);
        float r2 = 0.f;
#pragma unroll 1
        for (int i = 0; i < GSZ; ++i) {
            int p = g * GSZ + ((i + g) & (GSZ - 1));
            float dx = spx[p] - mx, dy = spy[p] - my, dz = spz[p] - mz;
            r2 = fmaxf(r2, dx * dx + dy * dy + dz * dz);
        }
        gmx[g] = mx; gmy[g] = my; gmz[g] = mz;
        gr[g] = sqrtf(r2) * 1.000002f + 1e-7f;      // safe upper bound of radius
        gub1[g] = 3e38f; gub2[g] = 3e38f; gai[g] = g * GSZ;   // force all-dirty at s=0
    }
    __syncthreads();
    int sel = ssel;

#pragma unroll 1
    for (int s = 0; s < SCENT; ++s) {
        const float cx = spx[sel], cy = spy[sel], cz = spz[sel];
        if (t == 0) {
            float* o = new_xyz + (size_t)(b * SCENT + s) * 3;
            o[0] = cx; o[1] = cy; o[2] = cz;
            shist[s] = (unsigned short)sel;
        }
        if (t < NGRP) {                        // prune tests (waves 0,1; 1 group/thread)
            int g = t;
            float dx = gmx[g] - cx, dy = gmy[g] - cy, dz = gmz[g] - cz;
            float dd = dx * dx + dy * dy + dz * dz;
            float sq = sqrtf(dd) * 0.999999f - gr[g];
            bool dirty = !(sq > 0.0f && sq * sq * 0.9999f >= gub1[g]);
            unsigned long long bm = __ballot(dirty);
            if (lane == 0) smaskv[w] = bm;
        }
        __syncthreads();                       // B1
        {
            int rank = 0;
#pragma unroll 1
            for (int half = 0; half < 2; ++half) {
                unsigned long long mm = smaskv[half];
                while (mm) {
                    int gl = __ffsll(mm) - 1; mm &= mm - 1;
                    if ((rank & 3) == w) {     // wave w handles every 4th dirty group
                        int g = half * 64 + gl;
                        int p = g * GSZ + lane;
                        float dx = spx[p] - cx, dy = spy[p] - cy, dz = spz[p] - cz;
                        float d  = dx * dx + dy * dy + dz * dz;
                        float dn = fminf(sdist[p], d);
                        sdist[p] = dn;
                        float v1 = dn, v2 = -1.0f; int i1 = p;
#pragma unroll
                        for (int off = 32; off >= 1; off >>= 1) {
                            float o1 = __shfl_down(v1, off);
                            float o2 = __shfl_down(v2, off);
                            int   oi = __shfl_down(i1, off);
                            float lo = fminf(v1, o1);
                            bool  tk = o1 > v1;
                            v1 = fmaxf(v1, o1);
                            i1 = tk ? oi : i1;
                            v2 = fmaxf(fmaxf(v2, o2), lo);
                        }
                        if (lane == 0) { gub1[g] = v1; gub2[g] = v2; gai[g] = i1; }
                    }
                    rank++;
                }
            }
        }
        __syncthreads();                       // B2
        // redundant global top-2 reduce (identical in every wave -> uniform)
        float v1, v2; int i1;
        {
            float a1 = gub1[lane], a2 = gub2[lane]; int ai = gai[lane];
            float b1 = gub1[64 + lane], b2 = gub2[64 + lane]; int bi = gai[64 + lane];
            v1 = a1; v2 = a2; i1 = ai;
            { float lo = fminf(v1, b1); bool tk = b1 > v1;
              v1 = fmaxf(v1, b1); i1 = tk ? bi : i1; v2 = fmaxf(fmaxf(v2, b2), lo); }
#pragma unroll
            for (int off = 32; off >= 1; off >>= 1) {
                float o1 = __shfl_down(v1, off);
                float o2 = __shfl_down(v2, off);
                int   oi = __shfl_down(i1, off);
                float lo = fminf(v1, o1);
                bool  tk = o1 > v1;
                v1 = fmaxf(v1, o1);
                i1 = tk ? oi : i1;
                v2 = fmaxf(fmaxf(v2, o2), lo);
            }
            v1 = __shfl(v1, 0); v2 = __shfl(v2, 0); i1 = __shfl(i1, 0);
        }
        const float thresh = __fmul_rn(v1, 0.999998f);
        if (v2 >= thresh) {
            // ---- exact f64 fallback (block-uniform, rare) ----
            int* scand = sscratch;
            int* pscnt = sscratch + 96;
            double* sdd = (double*)(sscratch + 128);    // [2][4]
            if (t == 0) *pscnt = 0;
            __syncthreads();
            for (int p = t; p < NPTS; p += FPS_T) {
                if (sdist[p] >= thresh) {
                    int slot = atomicAdd(pscnt, 1);
                    if (slot < CAP) scand[slot] = p;
                }
            }
            __syncthreads();
            const int m = *pscnt;
            if (m <= CAP) {
                double bd = -1.0; int borig = INT_MAX, bpos = 0;
#pragma unroll 1
                for (int k = 0; k < m; ++k) {
                    int pos = scand[k];
                    double pxd = (double)spx[pos], pyd = (double)spy[pos], pzd = (double)spz[pos];
                    double ddm = 1e10;
                    for (int i = t; i <= s; i += FPS_T) {
                        int h = shist[i];
                        double ddx = __dsub_rn(pxd, (double)spx[h]);
                        double ddy = __dsub_rn(pyd, (double)spy[h]);
                        double ddz = __dsub_rn(pzd, (double)spz[h]);
                        double d = __dadd_rn(__dadd_rn(__dmul_rn(ddx, ddx), __dmul_rn(ddy, ddy)),
                                             __dmul_rn(ddz, ddz));
                        ddm = fmin(ddm, d);
                    }
#pragma unroll
                    for (int off = 32; off >= 1; off >>= 1)
                        ddm = fmin(ddm, __shfl_down(ddm, off));
                    if (lane == 0) sdd[(k & 1) * 4 + w] = ddm;
                    __syncthreads();
                    double dd4 = fmin(fmin(sdd[(k & 1) * 4 + 0], sdd[(k & 1) * 4 + 1]),
                                      fmin(sdd[(k & 1) * 4 + 2], sdd[(k & 1) * 4 + 3]));
                    int orig = (int)sid[pos];
                    if (dd4 > bd || (dd4 == bd && orig < borig)) { bd = dd4; borig = orig; bpos = pos; }
                }
                sel = bpos;
            } else {
                // safety net: full exact scan (practically unreachable)
                double bv = -1.0; int borig = INT_MAX, bpos = 0;
                for (int p = t; p < NPTS; p += FPS_T) {
                    double pxd = (double)spx[p], pyd = (double)spy[p], pzd = (double)spz[p];
                    double ddm = 1e10;
                    for (int i = 0; i <= s; ++i) {
                        int h = shist[i];
                        double ddx = __dsub_rn(pxd, (double)spx[h]);
                        double ddy = __dsub_rn(pyd, (double)spy[h]);
                        double ddz = __dsub_rn(pzd, (double)spz[h]);
                        double d = __dadd_rn(__dadd_rn(__dmul_rn(ddx, ddx), __dmul_rn(ddy, ddy)),
                                             __dmul_rn(ddz, ddz));
                        ddm = fmin(ddm, d);
                    }
                    int orig = (int)sid[p];
                    if (ddm > bv || (ddm == bv && orig < borig)) { bv = ddm; borig = orig; bpos = p; }
                }
#pragma unroll
                for (int off = 32; off >= 1; off >>= 1) {
                    double ov = __shfl_down(bv, off);
                    int oo = __shfl_down(borig, off);
                    int op = __shfl_down(bpos, off);
                    if (ov > bv || (ov == bv && oo < borig)) { bv = ov; borig = oo; bpos = op; }
                }
                double* sfv = (double*)(sscratch + 160);
                int* sfo = sscratch + 176;
                int* sfp = sscratch + 184;
                if (lane == 0) { sfv[w] = bv; sfo[w] = borig; sfp[w] = bpos; }
                __syncthreads();
                bv = sfv[0]; borig = sfo[0]; bpos = sfp[0];
#pragma unroll
                for (int w2 = 1; w2 < 4; ++w2) {
                    double ov = sfv[w2]; int oo = sfo[w2]; int op = sfp[w2];
                    if (ov > bv || (ov == bv && oo < borig)) { bv = ov; borig = oo; bpos = op; }
                }
                sel = bpos;
            }
            __syncthreads();                  // protect sscratch before any reuse
        } else {
            sel = i1;                         // provably the unique f64 argmax
        }
    }
}

// ---------------------------------------------------------------------------
// Kernel 2: transpose points (B,D,N) -> (B,N,D).
// ---------------------------------------------------------------------------
__global__ void transpose_kernel(const float* __restrict__ pts, float* __restrict__ out) {
    __shared__ float tile[32][33];
    const int b  = blockIdx.z;
    const int n0 = blockIdx.x * 32, d0 = blockIdx.y * 32;
    const int tx = threadIdx.x, ty = threadIdx.y;   // block (32,8)
#pragma unroll
    for (int i = 0; i < 4; ++i)
        tile[ty + 8 * i][tx] =
            pts[(size_t)b * DFEAT * NPTS + (size_t)(d0 + ty + 8 * i) * NPTS + n0 + tx];
    __syncthreads();
#pragma unroll
    for (int i = 0; i < 4; ++i)
        out[(size_t)b * NPTS * DFEAT + (size_t)(n0 + ty + 8 * i) * DFEAT + d0 + tx] =
            tile[tx][ty + 8 * i];
}

// ---------------------------------------------------------------------------
// Kernel 3: KNN, one WAVE per query (f64-exact ordering, wave-parallel sorted
// top-32 with ballot/shfl insertion).
// ---------------------------------------------------------------------------
__global__ __launch_bounds__(256) void knn_kernel(const float* __restrict__ xyz,
                                                  const float* __restrict__ new_xyz,
                                                  int* __restrict__ knn_idx) {
    const int b    = blockIdx.y;
    const int wid  = threadIdx.x >> 6;
    const int lane = threadIdx.x & 63;
    const int qi   = blockIdx.x * 4 + wid;

    __shared__ float4 sp[2048];
    __shared__ double sp2[2048];

    const float* q = new_xyz + (size_t)(b * SCENT + qi) * 3;
    const double qx = (double)q[0], qy = (double)q[1], qz = (double)q[2];
    const double q2 = __dadd_rn(__dadd_rn(__dmul_rn(qx, qx), __dmul_rn(qy, qy)),
                                __dmul_rn(qz, qz));

    double ld   = DBL_MAX;
    int    li   = 0x7fffffff;
    double taud = DBL_MAX;
    int    taui = 0x7fffffff;

    const float* Xb = xyz + (size_t)b * NPTS * 3;
#pragma unroll 1
    for (int c = 0; c < 4; ++c) {
        __syncthreads();
#pragma unroll
        for (int r = 0; r < 8; ++r) {
            int pl = r * 256 + threadIdx.x;
            int p  = c * 2048 + pl;
            float x = Xb[3 * p + 0], y = Xb[3 * p + 1], z = Xb[3 * p + 2];
            sp[pl] = make_float4(x, y, z, 0.0f);
            double dx = (double)x, dy = (double)y, dz = (double)z;
            sp2[pl] = __dadd_rn(__dadd_rn(__dmul_rn(dx, dx), __dmul_rn(dy, dy)),
                                __dmul_rn(dz, dz));
        }
        __syncthreads();
#pragma unroll 1
        for (int i = 0; i < 32; ++i) {
            const int pl   = i * 64 + lane;
            const int pidx = c * 2048 + pl;
            float4 P = sp[pl];
            double px = (double)P.x, py = (double)P.y, pz = (double)P.z;
            double qp = __dadd_rn(__dadd_rn(__dmul_rn(qx, px), __dmul_rn(qy, py)),
                                  __dmul_rn(qz, pz));
            double d  = __dsub_rn(__dadd_rn(q2, sp2[pl]), __dmul_rn(2.0, qp));
            bool cand = (d < taud) || (d == taud && pidx < taui);
            unsigned long long m = __ballot(cand);
            while (m) {
                int sl = __ffsll((unsigned long long)m) - 1;
                m &= m - 1;
                double dv = __shfl(d, sl);
                int    iv = __shfl(pidx, sl);
                if (dv < taud || (dv == taud && iv < taui)) {
                    bool gt = (lane < 32) && (ld > dv || (ld == dv && li > iv));
                    unsigned long long gm = __ballot(gt);
                    double ud = __shfl_up(ld, 1);
                    int    ui = __shfl_up(li, 1);
                    if (gt) { ld = ud; li = ui; }
                    bool first = gt && ((lane == 0) || !((gm >> (lane - 1)) & 1ull));
                    if (first) { ld = dv; li = iv; }
                    taud = __shfl(ld, 31);
                    taui = __shfl(li, 31);
                }
            }
        }
    }
    if (lane < 32) knn_idx[(size_t)(b * SCENT + qi) * KNEIGH + lane] = li;
}

// ---------------------------------------------------------------------------
// Kernel 4: gather + 3-layer MLP (BN folded, fp32) + max over K.
// ---------------------------------------------------------------------------
__global__ __launch_bounds__(256) void mlp_kernel(
    const float* __restrict__ xyz, const float* __restrict__ new_xyz,
    const float* __restrict__ ptsT, const int* __restrict__ knn_idx,
    const float* __restrict__ w0, const float* __restrict__ g0,
    const float* __restrict__ b0, const float* __restrict__ m0,
    const float* __restrict__ v0, const float* __restrict__ w1,
    const float* __restrict__ g1, const float* __restrict__ b1,
    const float* __restrict__ m1, const float* __restrict__ v1,
    const float* __restrict__ w2, const float* __restrict__ g2,
    const float* __restrict__ b2, const float* __restrict__ m2,
    const float* __restrict__ v2, float* __restrict__ out_points) {

    __shared__ float regA[8192];
    __shared__ float regB[4096];
    __shared__ float prm[512];

    const int t = threadIdx.x;
    if (t < 64) {
        float a0v = g0[t] / sqrtf(v0[t] + 1e-5f);
        prm[t]       = a0v;
        prm[64 + t]  = b0[t] - m0[t] * a0v;
        float a1v = g1[t] / sqrtf(v1[t] + 1e-5f);
        prm[128 + t] = a1v;
        prm[192 + t] = b1[t] - m1[t] * a1v;
    } else if (t < 192) {
        int o = t - 64;
        float a2v = g2[o] / sqrtf(v2[o] + 1e-5f);
        prm[256 + o] = a2v;
        prm[384 + o] = b2[o] - m2[o] * a2v;
    }
    for (int idx = t; idx < 64 * 68; idx += 256) {
        int o = idx / 68, i = idx - o * 68;
        float v;
        if (i < 64)      v = w0[o * 67 + 3 + i];
        else if (i < 67) v = w0[o * 67 + (i - 64)];
        else             v = 0.0f;
        regA[idx] = v;
    }
    for (int idx = t; idx < 64 * 64; idx += 256) regB[idx] = w1[idx];
    __syncthreads();

    const int gid = blockIdx.x * 256 + t;
    const int sl  = gid >> 5;
    const int s   = sl & (SCENT - 1);
    const int b   = sl >> 11;
    const int nidx = knn_idx[gid];

    const float* q  = new_xyz + (size_t)(b * SCENT + s) * 3;
    const float* P3 = xyz + (size_t)(b * NPTS + nidx) * 3;
    const float dx = P3[0] - q[0], dy = P3[1] - q[1], dz = P3[2] - q[2];

    const float4* F = (const float4*)(ptsT + ((size_t)b * NPTS + nidx) * 64);
    float4 xv[17];
#pragma unroll
    for (int i = 0; i < 16; ++i) xv[i] = F[i];
    xv[16] = make_float4(dx, dy, dz, 0.0f);

    float h0[64];
    const float4* W0 = (const float4*)regA;
#pragma unroll
    for (int o = 0; o < 64; ++o) {
        float acc = 0.f;
#pragma unroll
        for (int i = 0; i < 17; ++i) {
            float4 w = W0[o * 17 + i];
            acc = fmaf(xv[i].x, w.x, acc);
            acc = fmaf(xv[i].y, w.y, acc);
            acc = fmaf(xv[i].z, w.z, acc);
            acc = fmaf(xv[i].w, w.w, acc);
        }
        h0[o] = fmaxf(fmaf(acc, prm[o], prm[64 + o]), 0.f);
    }
    __syncthreads();
    for (int idx = t; idx < 128 * 64; idx += 256) regA[idx] = w2[idx];
    __syncthreads();

    float h1[64];
    const float4* W1 = (const float4*)regB;
#pragma unroll
    for (int o = 0; o < 64; ++o) {
        float acc = 0.f;
#pragma unroll
        for (int i = 0; i < 16; ++i) {
            float4 w = W1[o * 16 + i];
            acc = fmaf(h0[4 * i + 0], w.x, acc);
            acc = fmaf(h0[4 * i + 1], w.y, acc);
            acc = fmaf(h0[4 * i + 2], w.z, acc);
            acc = fmaf(h0[4 * i + 3], w.w, acc);
        }
        h1[o] = fmaxf(fmaf(acc, prm[128 + o], prm[192 + o]), 0.f);
    }

    const float4* W2 = (const float4*)regA;
    float* outp = out_points + (size_t)b * 128 * SCENT + s;
    const int lane = t & 63;
#pragma unroll 1
    for (int o = 0; o < 128; ++o) {
        float acc = 0.f;
#pragma unroll
        for (int i = 0; i < 16; ++i) {
            float4 w = W2[o * 16 + i];
            acc = fmaf(h1[4 * i + 0], w.x, acc);
            acc = fmaf(h1[4 * i + 1], w.y, acc);
            acc = fmaf(h1[4 * i + 2], w.z, acc);
            acc = fmaf(h1[4 * i + 3], w.w, acc);
        }
        float y = fmaxf(fmaf(acc, prm[256 + o], prm[384 + o]), 0.f);
#pragma unroll
        for (int off = 16; off >= 1; off >>= 1) y = fmaxf(y, __shfl_xor(y, off));
        if ((lane & 31) == 0) outp[(size_t)o * SCENT] = y;
    }
}

// ---------------------------------------------------------------------------
extern "C" void kernel_launch(void* const* d_in, const int* in_sizes, int n_in,
                              void* d_out, int out_size, void* d_ws, size_t ws_size,
                              hipStream_t stream) {
    const float* xyz    = (const float*)d_in[0];
    const float* points = (const float*)d_in[1];
    const float* w0 = (const float*)d_in[2];
    const float* g0 = (const float*)d_in[3];
    const float* b0 = (const float*)d_in[4];
    const float* m0 = (const float*)d_in[5];
    const float* v0 = (const float*)d_in[6];
    const float* w1 = (const float*)d_in[7];
    const float* g1 = (const float*)d_in[8];
    const float* b1 = (const float*)d_in[9];
    const float* m1 = (const float*)d_in[10];
    const float* v1 = (const float*)d_in[11];
    const float* w2 = (const float*)d_in[12];
    const float* g2 = (const float*)d_in[13];
    const float* b2 = (const float*)d_in[14];
    const float* m2 = (const float*)d_in[15];
    const float* v2 = (const float*)d_in[16];

    float* out_xyz    = (float*)d_out;                               // (B,S,3)
    float* out_points = (float*)d_out + (size_t)BATCH * SCENT * 3;   // (B,128,S)

    char* ws = (char*)d_ws;
    int*   knn_idx = (int*)(ws + 32768);
    float* ptsT    = (float*)(ws + 32768 + (size_t)BATCH * SCENT * KNEIGH * 4);

    fps_kernel<<<BATCH, FPS_T, 0, stream>>>(xyz, out_xyz);
    transpose_kernel<<<dim3(NPTS / 32, DFEAT / 32, BATCH), dim3(32, 8), 0, stream>>>(points, ptsT);
    knn_kernel<<<dim3(SCENT / 4, BATCH), 256, 0, stream>>>(xyz, out_xyz, knn_idx);
    mlp_kernel<<<(BATCH * SCENT * KNEIGH) / 256, 256, 0, stream>>>(
        xyz, out_xyz, ptsT, knn_idx,
        w0, g0, b0, m0, v0, w1, g1, b1, m1, v1, w2, g2, b2, m2, v2, out_points);
}

// Round 6
// 3134.996 us; speedup vs baseline: 3.2012x; 3.2012x over previous
//
#include <hip/hip_runtime.h>
#include <cfloat>
#include <climits>

#define NPTS   8192
#define SCENT  2048
#define KNEIGH 32
#define BATCH  4
#define DFEAT  64
#define FPS_T  512
#define PPT    16      // points per thread, stride-FPS_T ownership
#define NW     8       // waves per block
#define CAP    64      // fallback candidate capacity

// ---------------------------------------------------------------------------
// Kernel 1: FPS. f32 fast path + exact-f64 fallback (proof as R3/R4: any f32
// rounding keeps relative error << 2e-6, so if no second point has dist32 >=
// v1*(1-2e-6), the f32 argmax IS the f64 argmax; otherwise candidates with
// dist32 >= v1*(1-2e-6) provably contain it and are re-scored exactly in f64
// with lexicographic (d, idx) = numpy argmax tie rule).
// R6 structure: 512 thr (2 waves/SIMD), 16 f32 pts/thread in registers,
// 4 independent max-chains, value+idx xor-butterfly, post-hoc tie count,
// ONE barrier per iteration (double-buffered slots).
// ---------------------------------------------------------------------------
__global__ __launch_bounds__(FPS_T, 1) void fps_kernel(const float* __restrict__ xyz,
                                                       float* __restrict__ new_xyz) {
    const int b = blockIdx.x, t = threadIdx.x;
    const int lane = t & 63, w = t >> 6;
    const float* X = xyz + (size_t)b * NPTS * 3;

    __shared__ float sx[NPTS], sy[NPTS], sz[NPTS];   // 96 KB point table
    __shared__ unsigned short shist[SCENT];          // selected indices (fallback)
    __shared__ float swv[2][NW];
    __shared__ int   swi[2][NW];
    __shared__ int   stw[2][NW];
    __shared__ int   scand[CAP];
    __shared__ int   scnt;
    __shared__ double sdd[2][NW];
    __shared__ double sfv[NW];
    __shared__ int   sfo[NW], sfp[NW];

    for (int p = t; p < NPTS; p += FPS_T) {
        sx[p] = X[3 * p + 0]; sy[p] = X[3 * p + 1]; sz[p] = X[3 * p + 2];
    }
    __syncthreads();

    float px[PPT], py[PPT], pz[PPT], dist[PPT];
#pragma unroll
    for (int j = 0; j < PPT; ++j) {
        int p = t + FPS_T * j;
        px[j] = sx[p]; py[j] = sy[p]; pz[j] = sz[p];
        dist[j] = 1e10f;
    }

    int cur = 0, buf = 0;
#pragma unroll 1
    for (int s = 0; s < SCENT; ++s) {
        const float cx = sx[cur], cy = sy[cur], cz = sz[cur];
        if (t == 0) {
            float* o = new_xyz + (size_t)(b * SCENT + s) * 3;
            o[0] = cx; o[1] = cy; o[2] = cz;
            shist[s] = (unsigned short)cur;
        }

        // ---- update + 4 independent (v,i) argmax chains ----
        float va = -1.f, vb = -1.f, vc = -1.f, vd = -1.f;
        int   ia = 0, ib = 0, ic = 0, id = 0;
#pragma unroll
        for (int j = 0; j < PPT; j += 4) {
            {
                float dx = px[j] - cx, dy = py[j] - cy, dz = pz[j] - cz;
                float d = fmaf(dx, dx, fmaf(dy, dy, dz * dz));
                float nd = fminf(dist[j], d); dist[j] = nd;
                bool g = nd > va; va = g ? nd : va; ia = g ? (t + FPS_T * j) : ia;
            }
            {
                float dx = px[j+1] - cx, dy = py[j+1] - cy, dz = pz[j+1] - cz;
                float d = fmaf(dx, dx, fmaf(dy, dy, dz * dz));
                float nd = fminf(dist[j+1], d); dist[j+1] = nd;
                bool g = nd > vb; vb = g ? nd : vb; ib = g ? (t + FPS_T * (j+1)) : ib;
            }
            {
                float dx = px[j+2] - cx, dy = py[j+2] - cy, dz = pz[j+2] - cz;
                float d = fmaf(dx, dx, fmaf(dy, dy, dz * dz));
                float nd = fminf(dist[j+2], d); dist[j+2] = nd;
                bool g = nd > vc; vc = g ? nd : vc; ic = g ? (t + FPS_T * (j+2)) : ic;
            }
            {
                float dx = px[j+3] - cx, dy = py[j+3] - cy, dz = pz[j+3] - cz;
                float d = fmaf(dx, dx, fmaf(dy, dy, dz * dz));
                float nd = fminf(dist[j+3], d); dist[j+3] = nd;
                bool g = nd > vd; vd = g ? nd : vd; id = g ? (t + FPS_T * (j+3)) : id;
            }
        }
        float v = va; int i1 = ia;
        if (vb > v) { v = vb; i1 = ib; }
        if (vc > v) { v = vc; i1 = ic; }
        if (vd > v) { v = vd; i1 = id; }

        // ---- wave butterfly (all lanes end with wave max; idx ties -> fallback) ----
#pragma unroll
        for (int off = 1; off < 64; off <<= 1) {
            float ov = __shfl_xor(v, off);
            int   oi = __shfl_xor(i1, off);
            if (ov > v) { v = ov; i1 = oi; }
        }
        // ---- post-hoc near-tie count vs wave threshold ----
        const float thw = __fmul_rn(v, 0.999998f);
        int cnt = 0;
#pragma unroll
        for (int j = 0; j < PPT; ++j) cnt += (dist[j] >= thw) ? 1 : 0;
        unsigned long long b2m = __ballot(cnt >= 2);
        unsigned long long b1m = __ballot(cnt >= 1);
        int tw = b2m ? 2 : ((__popcll(b1m) >= 2) ? 2 : 1);
        if (lane == 0) { swv[buf][w] = v; swi[buf][w] = i1; stw[buf][w] = tw; }
        __syncthreads();                                   // the ONE barrier

        // ---- redundant 8-slot merge (uniform result in every thread) ----
        float gv = swv[buf][0]; int gi = swi[buf][0]; int gt = stw[buf][0];
#pragma unroll
        for (int w2 = 1; w2 < NW; ++w2) {
            float ov = swv[buf][w2];
            if (ov > gv) { gv = ov; gi = swi[buf][w2]; gt = stw[buf][w2]; }
        }
        const float gth = __fmul_rn(gv, 0.999998f);
        int nw = 0;
#pragma unroll
        for (int w2 = 0; w2 < NW; ++w2) nw += (swv[buf][w2] >= gth) ? 1 : 0;

        if (nw >= 2 || gt >= 2) {
            // ---- exact f64 fallback (block-uniform, rare) ----
            if (t == 0) scnt = 0;
            __syncthreads();
#pragma unroll
            for (int j = 0; j < PPT; ++j) {
                if (dist[j] >= gth) {
                    int slot = atomicAdd(&scnt, 1);
                    if (slot < CAP) scand[slot] = t + FPS_T * j;
                }
            }
            __syncthreads();
            const int m = scnt;
            if (m <= CAP) {
                double bd = -1.0; int bi = INT_MAX;
#pragma unroll 1
                for (int k = 0; k < m; ++k) {
                    const int pidx = scand[k];
                    const double pxd = (double)sx[pidx], pyd = (double)sy[pidx],
                                 pzd = (double)sz[pidx];
                    double dd = 1e10;
                    for (int i = t; i <= s; i += FPS_T) {
                        int h = shist[i];
                        double ddx = __dsub_rn(pxd, (double)sx[h]);
                        double ddy = __dsub_rn(pyd, (double)sy[h]);
                        double ddz = __dsub_rn(pzd, (double)sz[h]);
                        double d = __dadd_rn(__dadd_rn(__dmul_rn(ddx, ddx), __dmul_rn(ddy, ddy)),
                                             __dmul_rn(ddz, ddz));
                        dd = fmin(dd, d);
                    }
#pragma unroll
                    for (int off = 32; off >= 1; off >>= 1)
                        dd = fmin(dd, __shfl_down(dd, off));
                    if (lane == 0) sdd[k & 1][w] = dd;
                    __syncthreads();
                    double ddm = sdd[k & 1][0];
#pragma unroll
                    for (int w2 = 1; w2 < NW; ++w2) ddm = fmin(ddm, sdd[k & 1][w2]);
                    if (ddm > bd || (ddm == bd && pidx < bi)) { bd = ddm; bi = pidx; }
                }
                cur = bi;
            } else {
                // safety net: full exact scan (practically unreachable)
                double bv = -1.0; int bi = INT_MAX;
#pragma unroll 1
                for (int j = 0; j < PPT; ++j) {
                    const double pxd = (double)px[j], pyd = (double)py[j], pzd = (double)pz[j];
                    double dd = 1e10;
                    for (int i = 0; i <= s; ++i) {
                        int h = shist[i];
                        double ddx = __dsub_rn(pxd, (double)sx[h]);
                        double ddy = __dsub_rn(pyd, (double)sy[h]);
                        double ddz = __dsub_rn(pzd, (double)sz[h]);
                        double d = __dadd_rn(__dadd_rn(__dmul_rn(ddx, ddx), __dmul_rn(ddy, ddy)),
                                             __dmul_rn(ddz, ddz));
                        dd = fmin(dd, d);
                    }
                    int pidx = t + FPS_T * j;
                    if (dd > bv || (dd == bv && pidx < bi)) { bv = dd; bi = pidx; }
                }
#pragma unroll
                for (int off = 32; off >= 1; off >>= 1) {
                    double ov = __shfl_down(bv, off);
                    int    oi = __shfl_down(bi, off);
                    if (ov > bv || (ov == bv && oi < bi)) { bv = ov; bi = oi; }
                }
                if (lane == 0) { sfv[w] = bv; sfo[w] = bi; }
                __syncthreads();
                bv = sfv[0]; bi = sfo[0];
#pragma unroll
                for (int w2 = 1; w2 < NW; ++w2) {
                    double ov = sfv[w2]; int oi = sfo[w2];
                    if (ov > bv || (ov == bv && oi < bi)) { bv = ov; bi = oi; }
                }
                cur = bi;
            }
            __syncthreads();
        } else {
            cur = gi;                        // provably the unique f64 argmax
        }
        buf ^= 1;
    }
}

// ---------------------------------------------------------------------------
// Kernel 2: transpose points (B,D,N) -> (B,N,D).
// ---------------------------------------------------------------------------
__global__ void transpose_kernel(const float* __restrict__ pts, float* __restrict__ out) {
    __shared__ float tile[32][33];
    const int b  = blockIdx.z;
    const int n0 = blockIdx.x * 32, d0 = blockIdx.y * 32;
    const int tx = threadIdx.x, ty = threadIdx.y;   // block (32,8)
#pragma unroll
    for (int i = 0; i < 4; ++i)
        tile[ty + 8 * i][tx] =
            pts[(size_t)b * DFEAT * NPTS + (size_t)(d0 + ty + 8 * i) * NPTS + n0 + tx];
    __syncthreads();
#pragma unroll
    for (int i = 0; i < 4; ++i)
        out[(size_t)b * NPTS * DFEAT + (size_t)(n0 + ty + 8 * i) * DFEAT + d0 + tx] =
            tile[tx][ty + 8 * i];
}

// ---------------------------------------------------------------------------
// Kernel 3: KNN, one WAVE per query (f64-exact ordering, wave-parallel sorted
// top-32 with ballot/shfl insertion).
// ---------------------------------------------------------------------------
__global__ __launch_bounds__(256) void knn_kernel(const float* __restrict__ xyz,
                                                  const float* __restrict__ new_xyz,
                                                  int* __restrict__ knn_idx) {
    const int b    = blockIdx.y;
    const int wid  = threadIdx.x >> 6;
    const int lane = threadIdx.x & 63;
    const int qi   = blockIdx.x * 4 + wid;

    __shared__ float4 sp[2048];
    __shared__ double sp2[2048];

    const float* q = new_xyz + (size_t)(b * SCENT + qi) * 3;
    const double qx = (double)q[0], qy = (double)q[1], qz = (double)q[2];
    const double q2 = __dadd_rn(__dadd_rn(__dmul_rn(qx, qx), __dmul_rn(qy, qy)),
                                __dmul_rn(qz, qz));

    double ld   = DBL_MAX;
    int    li   = 0x7fffffff;
    double taud = DBL_MAX;
    int    taui = 0x7fffffff;

    const float* Xb = xyz + (size_t)b * NPTS * 3;
#pragma unroll 1
    for (int c = 0; c < 4; ++c) {
        __syncthreads();
#pragma unroll
        for (int r = 0; r < 8; ++r) {
            int pl = r * 256 + threadIdx.x;
            int p  = c * 2048 + pl;
            float x = Xb[3 * p + 0], y = Xb[3 * p + 1], z = Xb[3 * p + 2];
            sp[pl] = make_float4(x, y, z, 0.0f);
            double dx = (double)x, dy = (double)y, dz = (double)z;
            sp2[pl] = __dadd_rn(__dadd_rn(__dmul_rn(dx, dx), __dmul_rn(dy, dy)),
                                __dmul_rn(dz, dz));
        }
        __syncthreads();
#pragma unroll 1
        for (int i = 0; i < 32; ++i) {
            const int pl   = i * 64 + lane;
            const int pidx = c * 2048 + pl;
            float4 P = sp[pl];
            double px = (double)P.x, py = (double)P.y, pz = (double)P.z;
            double qp = __dadd_rn(__dadd_rn(__dmul_rn(qx, px), __dmul_rn(qy, py)),
                                  __dmul_rn(qz, pz));
            double d  = __dsub_rn(__dadd_rn(q2, sp2[pl]), __dmul_rn(2.0, qp));
            bool cand = (d < taud) || (d == taud && pidx < taui);
            unsigned long long m = __ballot(cand);
            while (m) {
                int sl = __ffsll((unsigned long long)m) - 1;
                m &= m - 1;
                double dv = __shfl(d, sl);
                int    iv = __shfl(pidx, sl);
                if (dv < taud || (dv == taud && iv < taui)) {
                    bool gt = (lane < 32) && (ld > dv || (ld == dv && li > iv));
                    unsigned long long gm = __ballot(gt);
                    double ud = __shfl_up(ld, 1);
                    int    ui = __shfl_up(li, 1);
                    if (gt) { ld = ud; li = ui; }
                    bool first = gt && ((lane == 0) || !((gm >> (lane - 1)) & 1ull));
                    if (first) { ld = dv; li = iv; }
                    taud = __shfl(ld, 31);
                    taui = __shfl(li, 31);
                }
            }
        }
    }
    if (lane < 32) knn_idx[(size_t)(b * SCENT + qi) * KNEIGH + lane] = li;
}

// ---------------------------------------------------------------------------
// Kernel 4: gather + 3-layer MLP (BN folded, fp32) + max over K.
// ---------------------------------------------------------------------------
__global__ __launch_bounds__(256) void mlp_kernel(
    const float* __restrict__ xyz, const float* __restrict__ new_xyz,
    const float* __restrict__ ptsT, const int* __restrict__ knn_idx,
    const float* __restrict__ w0, const float* __restrict__ g0,
    const float* __restrict__ b0, const float* __restrict__ m0,
    const float* __restrict__ v0, const float* __restrict__ w1,
    const float* __restrict__ g1, const float* __restrict__ b1,
    const float* __restrict__ m1, const float* __restrict__ v1,
    const float* __restrict__ w2, const float* __restrict__ g2,
    const float* __restrict__ b2, const float* __restrict__ m2,
    const float* __restrict__ v2, float* __restrict__ out_points) {

    __shared__ float regA[8192];
    __shared__ float regB[4096];
    __shared__ float prm[512];

    const int t = threadIdx.x;
    if (t < 64) {
        float a0v = g0[t] / sqrtf(v0[t] + 1e-5f);
        prm[t]       = a0v;
        prm[64 + t]  = b0[t] - m0[t] * a0v;
        float a1v = g1[t] / sqrtf(v1[t] + 1e-5f);
        prm[128 + t] = a1v;
        prm[192 + t] = b1[t] - m1[t] * a1v;
    } else if (t < 192) {
        int o = t - 64;
        float a2v = g2[o] / sqrtf(v2[o] + 1e-5f);
        prm[256 + o] = a2v;
        prm[384 + o] = b2[o] - m2[o] * a2v;
    }
    for (int idx = t; idx < 64 * 68; idx += 256) {
        int o = idx / 68, i = idx - o * 68;
        float v;
        if (i < 64)      v = w0[o * 67 + 3 + i];
        else if (i < 67) v = w0[o * 67 + (i - 64)];
        else             v = 0.0f;
        regA[idx] = v;
    }
    for (int idx = t; idx < 64 * 64; idx += 256) regB[idx] = w1[idx];
    __syncthreads();

    const int gid = blockIdx.x * 256 + t;
    const int sl  = gid >> 5;
    const int s   = sl & (SCENT - 1);
    const int b   = sl >> 11;
    const int nidx = knn_idx[gid];

    const float* q  = new_xyz + (size_t)(b * SCENT + s) * 3;
    const float* P3 = xyz + (size_t)(b * NPTS + nidx) * 3;
    const float dx = P3[0] - q[0], dy = P3[1] - q[1], dz = P3[2] - q[2];

    const float4* F = (const float4*)(ptsT + ((size_t)b * NPTS + nidx) * 64);
    float4 xv[17];
#pragma unroll
    for (int i = 0; i < 16; ++i) xv[i] = F[i];
    xv[16] = make_float4(dx, dy, dz, 0.0f);

    float h0[64];
    const float4* W0 = (const float4*)regA;
#pragma unroll
    for (int o = 0; o < 64; ++o) {
        float acc = 0.f;
#pragma unroll
        for (int i = 0; i < 17; ++i) {
            float4 w = W0[o * 17 + i];
            acc = fmaf(xv[i].x, w.x, acc);
            acc = fmaf(xv[i].y, w.y, acc);
            acc = fmaf(xv[i].z, w.z, acc);
            acc = fmaf(xv[i].w, w.w, acc);
        }
        h0[o] = fmaxf(fmaf(acc, prm[o], prm[64 + o]), 0.f);
    }
    __syncthreads();
    for (int idx = t; idx < 128 * 64; idx += 256) regA[idx] = w2[idx];
    __syncthreads();

    float h1[64];
    const float4* W1 = (const float4*)regB;
#pragma unroll
    for (int o = 0; o < 64; ++o) {
        float acc = 0.f;
#pragma unroll
        for (int i = 0; i < 16; ++i) {
            float4 w = W1[o * 16 + i];
            acc = fmaf(h0[4 * i + 0], w.x, acc);
            acc = fmaf(h0[4 * i + 1], w.y, acc);
            acc = fmaf(h0[4 * i + 2], w.z, acc);
            acc = fmaf(h0[4 * i + 3], w.w, acc);
        }
        h1[o] = fmaxf(fmaf(acc, prm[128 + o], prm[192 + o]), 0.f);
    }

    const float4* W2 = (const float4*)regA;
    float* outp = out_points + (size_t)b * 128 * SCENT + s;
    const int lane = t & 63;
#pragma unroll 1
    for (int o = 0; o < 128; ++o) {
        float acc = 0.f;
#pragma unroll
        for (int i = 0; i < 16; ++i) {
            float4 w = W2[o * 16 + i];
            acc = fmaf(h1[4 * i + 0], w.x, acc);
            acc = fmaf(h1[4 * i + 1], w.y, acc);
            acc = fmaf(h1[4 * i + 2], w.z, acc);
            acc = fmaf(h1[4 * i + 3], w.w, acc);
        }
        float y = fmaxf(fmaf(acc, prm[256 + o], prm[384 + o]), 0.f);
#pragma unroll
        for (int off = 16; off >= 1; off >>= 1) y = fmaxf(y, __shfl_xor(y, off));
        if ((lane & 31) == 0) outp[(size_t)o * SCENT] = y;
    }
}

// ---------------------------------------------------------------------------
extern "C" void kernel_launch(void* const* d_in, const int* in_sizes, int n_in,
                              void* d_out, int out_size, void* d_ws, size_t ws_size,
                              hipStream_t stream) {
    const float* xyz    = (const float*)d_in[0];
    const float* points = (const float*)d_in[1];
    const float* w0 = (const float*)d_in[2];
    const float* g0 = (const float*)d_in[3];
    const float* b0 = (const float*)d_in[4];
    const float* m0 = (const float*)d_in[5];
    const float* v0 = (const float*)d_in[6];
    const float* w1 = (const float*)d_in[7];
    const float* g1 = (const float*)d_in[8];
    const float* b1 = (const float*)d_in[9];
    const float* m1 = (const float*)d_in[10];
    const float* v1 = (const float*)d_in[11];
    const float* w2 = (const float*)d_in[12];
    const float* g2 = (const float*)d_in[13];
    const float* b2 = (const float*)d_in[14];
    const float* m2 = (const float*)d_in[15];
    const float* v2 = (const float*)d_in[16];

    float* out_xyz    = (float*)d_out;                               // (B,S,3)
    float* out_points = (float*)d_out + (size_t)BATCH * SCENT * 3;   // (B,128,S)

    char* ws = (char*)d_ws;
    int*   knn_idx = (int*)(ws + 32768);
    float* ptsT    = (float*)(ws + 32768 + (size_t)BATCH * SCENT * KNEIGH * 4);

    fps_kernel<<<BATCH, FPS_T, 0, stream>>>(xyz, out_xyz);
    transpose_kernel<<<dim3(NPTS / 32, DFEAT / 32, BATCH), dim3(32, 8), 0, stream>>>(points, ptsT);
    knn_kernel<<<dim3(SCENT / 4, BATCH), 256, 0, stream>>>(xyz, out_xyz, knn_idx);
    mlp_kernel<<<(BATCH * SCENT * KNEIGH) / 256, 256, 0, stream>>>(
        xyz, out_xyz, ptsT, knn_idx,
        w0, g0, b0, m0, v0, w1, g1, b1, m1, v1, w2, g2, b2, m2, v2, out_points);
}

// Round 7
// 3080.462 us; speedup vs baseline: 3.2578x; 1.0177x over previous
//
#include <hip/hip_runtime.h>
#include <cfloat>
#include <climits>

#define NPTS   8192
#define SCENT  2048
#define KNEIGH 32
#define BATCH  4
#define DFEAT  64
#define FPS_T  512
#define PPT    16      // consecutive sorted points per thread
#define NW     8       // waves per block
#define NCELL  4096    // 16x16x16 Morton cells
#define CAP    64      // fallback candidate capacity

__device__ __forceinline__ int morton3(int x, int y, int z) {
    int m = 0;
#pragma unroll
    for (int k = 0; k < 4; ++k)
        m |= ((x >> k & 1) << (3 * k)) | ((y >> k & 1) << (3 * k + 1))
           | ((z >> k & 1) << (3 * k + 2));
    return m;
}

// ---------------------------------------------------------------------------
// Kernel 1: FPS. f32 fast path + exact-f64 fallback (proof: all f32 rounding
// keeps relative error << 2e-6; unique winner when no second point has
// dist32 >= v1*(1-2e-6); else f64 re-score of candidates vs full history with
// lexicographic (d, original-idx) = numpy argmax tie rule).
// R7: Morton-sorted points; thread owns 16 CONSECUTIVE points with center m_t
// and radius r_t. Skip update iff (|m_t-c|-r_t)^2 (conservative margins)
// >= myMax  -> provably no dist in chunk changes (exact skip). Persistent
// per-thread (myMax, mySec, myIdx). One barrier/iter.
// ---------------------------------------------------------------------------
__global__ __launch_bounds__(FPS_T, 1) void fps_kernel(const float* __restrict__ xyz,
                                                       float* __restrict__ new_xyz) {
    const int b = blockIdx.x, t = threadIdx.x;
    const int lane = t & 63, w = t >> 6;
    const float* X = xyz + (size_t)b * NPTS * 3;

    __shared__ float sx[NPTS], sy[NPTS], sz[NPTS];   // 96 KB sorted points
    __shared__ unsigned short sid[NPTS];             // sorted pos -> orig idx
    __shared__ unsigned short shist[SCENT];          // selected sorted positions
    __shared__ int   sscratch[NCELL];                // cell counters / offsets
    __shared__ float swv[2][NW];
    __shared__ int   swi[2][NW];
    __shared__ int   stw[2][NW];
    __shared__ int   scand[CAP];
    __shared__ int   scnt, ssel;
    __shared__ double sdd[2][NW];
    __shared__ double sfv[NW];
    __shared__ int   sfo[NW], sfp[NW];

    // ---- counting sort by Morton cell ----
    for (int i = t; i < NCELL; i += FPS_T) sscratch[i] = 0;
    __syncthreads();
    for (int p = t; p < NPTS; p += FPS_T) {
        float x = X[3 * p], y = X[3 * p + 1], z = X[3 * p + 2];
        int cx = min(max((int)((x + 4.0f) * 2.0f), 0), 15);
        int cy = min(max((int)((y + 4.0f) * 2.0f), 0), 15);
        int cz = min(max((int)((z + 4.0f) * 2.0f), 0), 15);
        atomicAdd(&sscratch[morton3(cx, cy, cz)], 1);
    }
    __syncthreads();
    if (t < 64) {                        // wave 0: in-place exclusive prefix sum
        int base = t * 64, sum = 0;
#pragma unroll 1
        for (int k = 0; k < 64; ++k) sum += sscratch[base + k];
        int run = sum;
#pragma unroll
        for (int off = 1; off < 64; off <<= 1) {
            int o = __shfl_up(run, off);
            if (t >= off) run += o;
        }
        int excl = run - sum;
#pragma unroll 1
        for (int k = 0; k < 64; ++k) {
            int tmp = sscratch[base + k];
            sscratch[base + k] = excl;
            excl += tmp;
        }
    }
    __syncthreads();
    for (int p = t; p < NPTS; p += FPS_T) {
        float x = X[3 * p], y = X[3 * p + 1], z = X[3 * p + 2];
        int cx = min(max((int)((x + 4.0f) * 2.0f), 0), 15);
        int cy = min(max((int)((y + 4.0f) * 2.0f), 0), 15);
        int cz = min(max((int)((z + 4.0f) * 2.0f), 0), 15);
        int pos = atomicAdd(&sscratch[morton3(cx, cy, cz)], 1);
        sx[pos] = x; sy[pos] = y; sz[pos] = z;
        sid[pos] = (unsigned short)p;
    }
    __syncthreads();
    for (int p = t; p < NPTS; p += FPS_T)
        if (sid[p] == 0) ssel = p;
    __syncthreads();

    // ---- per-thread chunk: 16 consecutive sorted points ----
    const int base = t * PPT;
    float px[PPT], py[PPT], pz[PPT], dist[PPT];
    float mx = 0.f, my = 0.f, mz = 0.f;
#pragma unroll
    for (int j = 0; j < PPT; ++j) {
        px[j] = sx[base + j]; py[j] = sy[base + j]; pz[j] = sz[base + j];
        dist[j] = 1e10f;
        mx += px[j]; my += py[j]; mz += pz[j];
    }
    mx *= (1.0f / PPT); my *= (1.0f / PPT); mz *= (1.0f / PPT);
    float r2 = 0.f;
#pragma unroll
    for (int j = 0; j < PPT; ++j) {
        float dx = px[j] - mx, dy = py[j] - my, dz = pz[j] - mz;
        r2 = fmaxf(r2, fmaf(dx, dx, fmaf(dy, dy, dz * dz)));
    }
    const float rt = sqrtf(r2) * 1.000002f + 1e-7f;   // safe radius upper bound

    float myMax = 3e38f, mySec = -1.f;    // 3e38 forces scan at s=0
    int   myIdx = base;
    int   sel = ssel, buf = 0;

#pragma unroll 1
    for (int s = 0; s < SCENT; ++s) {
        const float ccx = sx[sel], ccy = sy[sel], ccz = sz[sel];
        if (t == 0) {
            float* o = new_xyz + (size_t)(b * SCENT + s) * 3;
            o[0] = ccx; o[1] = ccy; o[2] = ccz;
            shist[s] = (unsigned short)sel;
        }
        // ---- chunk prune test (exact skip, conservative margins) ----
        float ddx = mx - ccx, ddy = my - ccy, ddz = mz - ccz;
        float cdd = fmaf(ddx, ddx, fmaf(ddy, ddy, ddz * ddz));
        float sq  = sqrtf(cdd) * 0.999999f - rt;
        bool scan = !(sq > 0.0f && sq * sq * 0.9999f >= myMax);
        if (scan) {
            float u1 = -1.f, u2 = -1.f; int ui = base;
            float x1 = -1.f, x2 = -1.f; int xi = base;
#pragma unroll
            for (int j = 0; j < PPT; j += 2) {
                {
                    float dx = px[j] - ccx, dy = py[j] - ccy, dz = pz[j] - ccz;
                    float d  = fmaf(dx, dx, fmaf(dy, dy, dz * dz));
                    float nd = fminf(dist[j], d); dist[j] = nd;
                    bool g = nd > u1;
                    u2 = fmaxf(u2, fminf(u1, nd));
                    u1 = fmaxf(u1, nd);
                    ui = g ? (base + j) : ui;
                }
                {
                    float dx = px[j+1] - ccx, dy = py[j+1] - ccy, dz = pz[j+1] - ccz;
                    float d  = fmaf(dx, dx, fmaf(dy, dy, dz * dz));
                    float nd = fminf(dist[j+1], d); dist[j+1] = nd;
                    bool g = nd > x1;
                    x2 = fmaxf(x2, fminf(x1, nd));
                    x1 = fmaxf(x1, nd);
                    xi = g ? (base + j + 1) : xi;
                }
            }
            float lo = fminf(u1, x1);
            bool tk = x1 > u1;
            myMax = fmaxf(u1, x1);
            myIdx = tk ? xi : ui;
            mySec = fmaxf(fmaxf(u2, x2), lo);
        }
        // ---- wave reduce: value-only butterfly + winner by ballot ----
        float v = myMax;
#pragma unroll
        for (int off = 1; off < 64; off <<= 1) v = fmaxf(v, __shfl_xor(v, off));
        unsigned long long win = __ballot(myMax == v);
        int i1 = __shfl(myIdx, __ffsll(win) - 1);
        // ---- near-tie flags (== old per-point count semantics) ----
        const float thw = __fmul_rn(v, 0.999998f);
        unsigned long long b1 = __ballot(myMax >= thw);
        unsigned long long b2 = __ballot(mySec >= thw);
        int tw = ((__popcll(b1) >= 2) || b2) ? 2 : 1;
        if (lane == 0) { swv[buf][w] = v; swi[buf][w] = i1; stw[buf][w] = tw; }
        __syncthreads();                                   // the ONE barrier
        // ---- global merge: lane-parallel slots + 3-step butterfly ----
        float s0 = swv[buf][lane & 7];
        float gv = s0;
#pragma unroll
        for (int off = 1; off < 8; off <<= 1) gv = fmaxf(gv, __shfl_xor(gv, off));
        const float gth = __fmul_rn(gv, 0.999998f);
        unsigned long long bm = __ballot(s0 >= gth) & 0xFFull;
        unsigned long long wm = __ballot(s0 == gv) & 0xFFull;
        int nslots = __popcll(bm);
        int wslot  = __ffsll(wm) - 1;
        int gi = swi[buf][wslot];
        int gt = stw[buf][wslot];

        if (nslots >= 2 || gt >= 2) {
            // ---- exact f64 fallback (block-uniform, rare) ----
            if (t == 0) scnt = 0;
            __syncthreads();
#pragma unroll
            for (int j = 0; j < PPT; ++j) {
                if (dist[j] >= gth) {
                    int slot = atomicAdd(&scnt, 1);
                    if (slot < CAP) scand[slot] = base + j;
                }
            }
            __syncthreads();
            const int m = scnt;
            if (m <= CAP) {
                double bd = -1.0; int borig = INT_MAX, bpos = 0;
#pragma unroll 1
                for (int k = 0; k < m; ++k) {
                    const int pos = scand[k];
                    const double pxd = (double)sx[pos], pyd = (double)sy[pos],
                                 pzd = (double)sz[pos];
                    double dd = 1e10;
                    for (int i = t; i <= s; i += FPS_T) {
                        int h = shist[i];
                        double dx = __dsub_rn(pxd, (double)sx[h]);
                        double dy = __dsub_rn(pyd, (double)sy[h]);
                        double dz = __dsub_rn(pzd, (double)sz[h]);
                        double d  = __dadd_rn(__dadd_rn(__dmul_rn(dx, dx), __dmul_rn(dy, dy)),
                                              __dmul_rn(dz, dz));
                        dd = fmin(dd, d);
                    }
#pragma unroll
                    for (int off = 32; off >= 1; off >>= 1)
                        dd = fmin(dd, __shfl_down(dd, off));
                    if (lane == 0) sdd[k & 1][w] = dd;
                    __syncthreads();
                    double ddm = sdd[k & 1][0];
#pragma unroll
                    for (int w2 = 1; w2 < NW; ++w2) ddm = fmin(ddm, sdd[k & 1][w2]);
                    int orig = (int)sid[pos];
                    if (ddm > bd || (ddm == bd && orig < borig)) {
                        bd = ddm; borig = orig; bpos = pos;
                    }
                }
                sel = bpos;
            } else {
                // safety net: full exact scan (practically unreachable)
                double bv = -1.0; int borig = INT_MAX, bpos = 0;
#pragma unroll 1
                for (int j = 0; j < PPT; ++j) {
                    const double pxd = (double)px[j], pyd = (double)py[j], pzd = (double)pz[j];
                    double dd = 1e10;
                    for (int i = 0; i <= s; ++i) {
                        int h = shist[i];
                        double dx = __dsub_rn(pxd, (double)sx[h]);
                        double dy = __dsub_rn(pyd, (double)sy[h]);
                        double dz = __dsub_rn(pzd, (double)sz[h]);
                        double d  = __dadd_rn(__dadd_rn(__dmul_rn(dx, dx), __dmul_rn(dy, dy)),
                                              __dmul_rn(dz, dz));
                        dd = fmin(dd, d);
                    }
                    int orig = (int)sid[base + j];
                    if (dd > bv || (dd == bv && orig < borig)) {
                        bv = dd; borig = orig; bpos = base + j;
                    }
                }
#pragma unroll
                for (int off = 32; off >= 1; off >>= 1) {
                    double ov = __shfl_down(bv, off);
                    int    oo = __shfl_down(borig, off);
                    int    op = __shfl_down(bpos, off);
                    if (ov > bv || (ov == bv && oo < borig)) { bv = ov; borig = oo; bpos = op; }
                }
                if (lane == 0) { sfv[w] = bv; sfo[w] = borig; sfp[w] = bpos; }
                __syncthreads();
                bv = sfv[0]; borig = sfo[0]; bpos = sfp[0];
#pragma unroll
                for (int w2 = 1; w2 < NW; ++w2) {
                    double ov = sfv[w2]; int oo = sfo[w2]; int op = sfp[w2];
                    if (ov > bv || (ov == bv && oo < borig)) { bv = ov; borig = oo; bpos = op; }
                }
                sel = bpos;
            }
            __syncthreads();
        } else {
            sel = gi;                        // provably the unique f64 argmax
        }
        buf ^= 1;
    }
}

// ---------------------------------------------------------------------------
// Kernel 2: transpose points (B,D,N) -> (B,N,D).
// ---------------------------------------------------------------------------
__global__ void transpose_kernel(const float* __restrict__ pts, float* __restrict__ out) {
    __shared__ float tile[32][33];
    const int b  = blockIdx.z;
    const int n0 = blockIdx.x * 32, d0 = blockIdx.y * 32;
    const int tx = threadIdx.x, ty = threadIdx.y;   // block (32,8)
#pragma unroll
    for (int i = 0; i < 4; ++i)
        tile[ty + 8 * i][tx] =
            pts[(size_t)b * DFEAT * NPTS + (size_t)(d0 + ty + 8 * i) * NPTS + n0 + tx];
    __syncthreads();
#pragma unroll
    for (int i = 0; i < 4; ++i)
        out[(size_t)b * NPTS * DFEAT + (size_t)(n0 + ty + 8 * i) * DFEAT + d0 + tx] =
            tile[tx][ty + 8 * i];
}

// ---------------------------------------------------------------------------
// Kernel 3: KNN, one WAVE per query (f64-exact ordering, wave-parallel sorted
// top-32 with ballot/shfl insertion).
// ---------------------------------------------------------------------------
__global__ __launch_bounds__(256) void knn_kernel(const float* __restrict__ xyz,
                                                  const float* __restrict__ new_xyz,
                                                  int* __restrict__ knn_idx) {
    const int b    = blockIdx.y;
    const int wid  = threadIdx.x >> 6;
    const int lane = threadIdx.x & 63;
    const int qi   = blockIdx.x * 4 + wid;

    __shared__ float4 sp[2048];
    __shared__ double sp2[2048];

    const float* q = new_xyz + (size_t)(b * SCENT + qi) * 3;
    const double qx = (double)q[0], qy = (double)q[1], qz = (double)q[2];
    const double q2 = __dadd_rn(__dadd_rn(__dmul_rn(qx, qx), __dmul_rn(qy, qy)),
                                __dmul_rn(qz, qz));

    double ld   = DBL_MAX;
    int    li   = 0x7fffffff;
    double taud = DBL_MAX;
    int    taui = 0x7fffffff;

    const float* Xb = xyz + (size_t)b * NPTS * 3;
#pragma unroll 1
    for (int c = 0; c < 4; ++c) {
        __syncthreads();
#pragma unroll
        for (int r = 0; r < 8; ++r) {
            int pl = r * 256 + threadIdx.x;
            int p  = c * 2048 + pl;
            float x = Xb[3 * p + 0], y = Xb[3 * p + 1], z = Xb[3 * p + 2];
            sp[pl] = make_float4(x, y, z, 0.0f);
            double dx = (double)x, dy = (double)y, dz = (double)z;
            sp2[pl] = __dadd_rn(__dadd_rn(__dmul_rn(dx, dx), __dmul_rn(dy, dy)),
                                __dmul_rn(dz, dz));
        }
        __syncthreads();
#pragma unroll 1
        for (int i = 0; i < 32; ++i) {
            const int pl   = i * 64 + lane;
            const int pidx = c * 2048 + pl;
            float4 P = sp[pl];
            double px = (double)P.x, py = (double)P.y, pz = (double)P.z;
            double qp = __dadd_rn(__dadd_rn(__dmul_rn(qx, px), __dmul_rn(qy, py)),
                                  __dmul_rn(qz, pz));
            double d  = __dsub_rn(__dadd_rn(q2, sp2[pl]), __dmul_rn(2.0, qp));
            bool cand = (d < taud) || (d == taud && pidx < taui);
            unsigned long long m = __ballot(cand);
            while (m) {
                int sl = __ffsll((unsigned long long)m) - 1;
                m &= m - 1;
                double dv = __shfl(d, sl);
                int    iv = __shfl(pidx, sl);
                if (dv < taud || (dv == taud && iv < taui)) {
                    bool gt = (lane < 32) && (ld > dv || (ld == dv && li > iv));
                    unsigned long long gm = __ballot(gt);
                    double ud = __shfl_up(ld, 1);
                    int    ui = __shfl_up(li, 1);
                    if (gt) { ld = ud; li = ui; }
                    bool first = gt && ((lane == 0) || !((gm >> (lane - 1)) & 1ull));
                    if (first) { ld = dv; li = iv; }
                    taud = __shfl(ld, 31);
                    taui = __shfl(li, 31);
                }
            }
        }
    }
    if (lane < 32) knn_idx[(size_t)(b * SCENT + qi) * KNEIGH + lane] = li;
}

// ---------------------------------------------------------------------------
// Kernel 4: gather + 3-layer MLP (BN folded, fp32) + max over K.
// ---------------------------------------------------------------------------
__global__ __launch_bounds__(256) void mlp_kernel(
    const float* __restrict__ xyz, const float* __restrict__ new_xyz,
    const float* __restrict__ ptsT, const int* __restrict__ knn_idx,
    const float* __restrict__ w0, const float* __restrict__ g0,
    const float* __restrict__ b0, const float* __restrict__ m0,
    const float* __restrict__ v0, const float* __restrict__ w1,
    const float* __restrict__ g1, const float* __restrict__ b1,
    const float* __restrict__ m1, const float* __restrict__ v1,
    const float* __restrict__ w2, const float* __restrict__ g2,
    const float* __restrict__ b2, const float* __restrict__ m2,
    const float* __restrict__ v2, float* __restrict__ out_points) {

    __shared__ float regA[8192];
    __shared__ float regB[4096];
    __shared__ float prm[512];

    const int t = threadIdx.x;
    if (t < 64) {
        float a0v = g0[t] / sqrtf(v0[t] + 1e-5f);
        prm[t]       = a0v;
        prm[64 + t]  = b0[t] - m0[t] * a0v;
        float a1v = g1[t] / sqrtf(v1[t] + 1e-5f);
        prm[128 + t] = a1v;
        prm[192 + t] = b1[t] - m1[t] * a1v;
    } else if (t < 192) {
        int o = t - 64;
        float a2v = g2[o] / sqrtf(v2[o] + 1e-5f);
        prm[256 + o] = a2v;
        prm[384 + o] = b2[o] - m2[o] * a2v;
    }
    for (int idx = t; idx < 64 * 68; idx += 256) {
        int o = idx / 68, i = idx - o * 68;
        float v;
        if (i < 64)      v = w0[o * 67 + 3 + i];
        else if (i < 67) v = w0[o * 67 + (i - 64)];
        else             v = 0.0f;
        regA[idx] = v;
    }
    for (int idx = t; idx < 64 * 64; idx += 256) regB[idx] = w1[idx];
    __syncthreads();

    const int gid = blockIdx.x * 256 + t;
    const int sl  = gid >> 5;
    const int s   = sl & (SCENT - 1);
    const int b   = sl >> 11;
    const int nidx = knn_idx[gid];

    const float* q  = new_xyz + (size_t)(b * SCENT + s) * 3;
    const float* P3 = xyz + (size_t)(b * NPTS + nidx) * 3;
    const float dx = P3[0] - q[0], dy = P3[1] - q[1], dz = P3[2] - q[2];

    const float4* F = (const float4*)(ptsT + ((size_t)b * NPTS + nidx) * 64);
    float4 xv[17];
#pragma unroll
    for (int i = 0; i < 16; ++i) xv[i] = F[i];
    xv[16] = make_float4(dx, dy, dz, 0.0f);

    float h0[64];
    const float4* W0 = (const float4*)regA;
#pragma unroll
    for (int o = 0; o < 64; ++o) {
        float acc = 0.f;
#pragma unroll
        for (int i = 0; i < 17; ++i) {
            float4 w = W0[o * 17 + i];
            acc = fmaf(xv[i].x, w.x, acc);
            acc = fmaf(xv[i].y, w.y, acc);
            acc = fmaf(xv[i].z, w.z, acc);
            acc = fmaf(xv[i].w, w.w, acc);
        }
        h0[o] = fmaxf(fmaf(acc, prm[o], prm[64 + o]), 0.f);
    }
    __syncthreads();
    for (int idx = t; idx < 128 * 64; idx += 256) regA[idx] = w2[idx];
    __syncthreads();

    float h1[64];
    const float4* W1 = (const float4*)regB;
#pragma unroll
    for (int o = 0; o < 64; ++o) {
        float acc = 0.f;
#pragma unroll
        for (int i = 0; i < 16; ++i) {
            float4 w = W1[o * 16 + i];
            acc = fmaf(h0[4 * i + 0], w.x, acc);
            acc = fmaf(h0[4 * i + 1], w.y, acc);
            acc = fmaf(h0[4 * i + 2], w.z, acc);
            acc = fmaf(h0[4 * i + 3], w.w, acc);
        }
        h1[o] = fmaxf(fmaf(acc, prm[128 + o], prm[192 + o]), 0.f);
    }

    const float4* W2 = (const float4*)regA;
    float* outp = out_points + (size_t)b * 128 * SCENT + s;
    const int lane = t & 63;
#pragma unroll 1
    for (int o = 0; o < 128; ++o) {
        float acc = 0.f;
#pragma unroll
        for (int i = 0; i < 16; ++i) {
            float4 w = W2[o * 16 + i];
            acc = fmaf(h1[4 * i + 0], w.x, acc);
            acc = fmaf(h1[4 * i + 1], w.y, acc);
            acc = fmaf(h1[4 * i + 2], w.z, acc);
            acc = fmaf(h1[4 * i + 3], w.w, acc);
        }
        float y = fmaxf(fmaf(acc, prm[256 + o], prm[384 + o]), 0.f);
#pragma unroll
        for (int off = 16; off >= 1; off >>= 1) y = fmaxf(y, __shfl_xor(y, off));
        if ((lane & 31) == 0) outp[(size_t)o * SCENT] = y;
    }
}

// ---------------------------------------------------------------------------
extern "C" void kernel_launch(void* const* d_in, const int* in_sizes, int n_in,
                              void* d_out, int out_size, void* d_ws, size_t ws_size,
                              hipStream_t stream) {
    const float* xyz    = (const float*)d_in[0];
    const float* points = (const float*)d_in[1];
    const float* w0 = (const float*)d_in[2];
    const float* g0 = (const float*)d_in[3];
    const float* b0 = (const float*)d_in[4];
    const float* m0 = (const float*)d_in[5];
    const float* v0 = (const float*)d_in[6];
    const float* w1 = (const float*)d_in[7];
    const float* g1 = (const float*)d_in[8];
    const float* b1 = (const float*)d_in[9];
    const float* m1 = (const float*)d_in[10];
    const float* v1 = (const float*)d_in[11];
    const float* w2 = (const float*)d_in[12];
    const float* g2 = (const float*)d_in[13];
    const float* b2 = (const float*)d_in[14];
    const float* m2 = (const float*)d_in[15];
    const float* v2 = (const float*)d_in[16];

    float* out_xyz    = (float*)d_out;                               // (B,S,3)
    float* out_points = (float*)d_out + (size_t)BATCH * SCENT * 3;   // (B,128,S)

    char* ws = (char*)d_ws;
    int*   knn_idx = (int*)(ws + 32768);
    float* ptsT    = (float*)(ws + 32768 + (size_t)BATCH * SCENT * KNEIGH * 4);

    fps_kernel<<<BATCH, FPS_T, 0, stream>>>(xyz, out_xyz);
    transpose_kernel<<<dim3(NPTS / 32, DFEAT / 32, BATCH), dim3(32, 8), 0, stream>>>(points, ptsT);
    knn_kernel<<<dim3(SCENT / 4, BATCH), 256, 0, stream>>>(xyz, out_xyz, knn_idx);
    mlp_kernel<<<(BATCH * SCENT * KNEIGH) / 256, 256, 0, stream>>>(
        xyz, out_xyz, ptsT, knn_idx,
        w0, g0, b0, m0, v0, w1, g1, b1, m1, v1, w2, g2, b2, m2, v2, out_points);
}